// Round 1
// baseline (501.078 us; speedup 1.0000x reference)
//
#include <hip/hip_runtime.h>

#define PAST 12
#define FUTURE 12
#define NB 64
#define NL 256
#define ND 512
#define NW 244  // NL - PAST

#define LROWS 160   // y-rows per block: 128 output w's + 11 halo, padded to 10 MFMA m-tiles
#define BN2 128     // e-columns per block
#define BK2 32      // K-step

typedef unsigned short ushort_t;
typedef __attribute__((ext_vector_type(8))) short short8;
typedef __attribute__((ext_vector_type(4))) float floatx4;

__device__ inline unsigned int f2bf(float x) {
    unsigned int u = __float_as_uint(x);
    return (u + 0x7fffu + ((u >> 16) & 1u)) >> 16;  // RNE
}

// ---------------- Stage 0: W_s fp32 -> bf16, and S[e] = sum_d W_s[e][d] ----------------
__global__ __launch_bounds__(256) void prep_ws(
    const float* __restrict__ Ws, ushort_t* __restrict__ Wsb, float* __restrict__ S)
{
    const int row = blockIdx.x;       // 0..511
    const int t = threadIdx.x;        // 0..255
    const float2 v = *(const float2*)(Ws + (size_t)row * ND + t * 2);
    *(unsigned int*)(Wsb + (size_t)row * ND + t * 2) = f2bf(v.x) | (f2bf(v.y) << 16);
    float s = v.x + v.y;
#pragma unroll
    for (int o = 32; o > 0; o >>= 1) s += __shfl_down(s, o);
    __shared__ float red[4];
    if ((t & 63) == 0) red[t >> 6] = s;
    __syncthreads();
    if (t == 0) S[row] = red[0] + red[1] + red[2] + red[3];
}

// ---------------- Fused: (inp @ Ws^T) tile in LDS -> temporal mix -> Out ----------------
// Block covers y rows [lt*128, lt*128+160) of batch b (row>=256 clamped, never consumed),
// e-cols [n0, n0+128). Output w in [lt*128, min(lt*128+128, 244)).

#define STAGE_A_LOAD(k0) do { \
    _Pragma("unroll") \
    for (int c = 0; c < 5; ++c) av[c] = *(const float4*)(aptr[c] + (k0)); \
} while (0)

#define STAGE_A_WRITE(dst) do { \
    _Pragma("unroll") \
    for (int c = 0; c < 5; ++c) { \
        uint2 o; \
        o.x = f2bf(av[c].x) | (f2bf(av[c].y) << 16); \
        o.y = f2bf(av[c].z) | (f2bf(av[c].w) << 16); \
        *(uint2*)((dst) + awoff + c * 1024) = o; \
    } \
} while (0)

#define STAGE_B(k0, dst) do { \
    _Pragma("unroll") \
    for (int r = 0; r < 2; ++r) { \
        const ushort_t* gb = Bm + (size_t)(n0 + (tid >> 2) + r * 64) * ND + (k0) + (tid & 3) * 8; \
        __builtin_amdgcn_global_load_lds( \
            (const __attribute__((address_space(1))) unsigned int*)gb, \
            (__attribute__((address_space(3))) unsigned int*)((dst) + r * 2048 + tid * 8), \
            16, 0, 0); \
    } \
} while (0)

#define GEMM_STEP(cura, curb) do { \
    const ushort_t* a_base = (cura) + (wm + (lane & 15)) * BK2 + (lane >> 4) * 8; \
    const ushort_t* b_base = (curb) + (wn + (lane & 15)) * BK2 + (lane >> 4) * 8; \
    short8 af[5], bq[4]; \
    _Pragma("unroll") \
    for (int mt = 0; mt < 5; ++mt) af[mt] = *(const short8*)(a_base + mt * 16 * BK2); \
    _Pragma("unroll") \
    for (int nt = 0; nt < 4; ++nt) bq[nt] = *(const short8*)(b_base + nt * 16 * BK2); \
    _Pragma("unroll") \
    for (int mt = 0; mt < 5; ++mt) \
    _Pragma("unroll") \
    for (int nt = 0; nt < 4; ++nt) \
        acc[mt][nt] = __builtin_amdgcn_mfma_f32_16x16x32_bf16(af[mt], bq[nt], acc[mt][nt], 0, 0, 0); \
} while (0)

#define FULL_STEP(k, cura, curb, nxta, nxtb) do { \
    if ((k) < 15) { STAGE_A_LOAD(((k) + 1) * BK2); STAGE_B(((k) + 1) * BK2, nxtb); } \
    GEMM_STEP(cura, curb); \
    if ((k) < 15) STAGE_A_WRITE(nxta); \
    __syncthreads(); \
} while (0)

__global__ __launch_bounds__(256) void fused(
    const float* __restrict__ A,       // inp [64,256,512] fp32
    const ushort_t* __restrict__ Bm,   // Ws bf16 [512,512]
    const float* __restrict__ Wt,      // [12,12]
    const float* __restrict__ bt,      // [12]
    const float* __restrict__ bs,      // [512]
    const float* __restrict__ S,       // [512]
    float* __restrict__ Out)           // [64,244,12,512] fp32
{
    // 40 KB LDS, two lives: GEMM staging As0|As1|Bs0|Bs1 (18 KB), then y tile [160][128] bf16.
    __shared__ __align__(16) ushort_t lds[LROWS * BN2];

    const int tid  = threadIdx.x;
    const int lane = tid & 63;
    const int wave = tid >> 6;
    const int wm = (wave >> 1) * 80;   // waves 2x2: each owns 80 rows x 64 cols
    const int wn = (wave & 1) * 64;
    const int n0 = blockIdx.x * BN2;
    const int b  = blockIdx.y >> 1;
    const int lt = blockIdx.y & 1;

    ushort_t* const As0 = lds;
    ushort_t* const As1 = lds + LROWS * BK2;
    ushort_t* const Bs0 = lds + 2 * LROWS * BK2;
    ushort_t* const Bs1 = lds + 2 * LROWS * BK2 + BN2 * BK2;

    // A staging map: i = c*256+tid in [0,1280): row = i>>3, 8 float4-chunks per 32-wide row.
    const float* aptr[5];
#pragma unroll
    for (int c = 0; c < 5; ++c) {
        const int i = c * 256 + tid;
        const int row = i >> 3;
        const int rcl = (lt * 128 + row < NL) ? (lt * 128 + row) : (NL - 1);  // clamp halo
        aptr[c] = A + ((size_t)b * NL + rcl) * ND + (i & 7) * 4;
    }
    const int awoff = tid * 4;   // ushort offset; +c*1024 gives linear i*4

    float4 av[5];
    floatx4 acc[5][4] = {};

    // prologue: tile 0 into buf0
    STAGE_A_LOAD(0);
    STAGE_B(0, Bs0);
    STAGE_A_WRITE(As0);
    __syncthreads();

    for (int k = 0; k < 16; k += 2) {
        FULL_STEP(k,     As0, Bs0, As1, Bs1);
        FULL_STEP(k + 1, As1, Bs1, As0, Bs0);
    }

    // epilogue: acc -> y tile in LDS (bf16), overwriting staging area.
    // C/D layout: col = lane&15 (e), row = (lane>>4)*4 + r (l).
#pragma unroll
    for (int mt = 0; mt < 5; ++mt) {
        const int r0 = wm + mt * 16 + (lane >> 4) * 4;
#pragma unroll
        for (int nt = 0; nt < 4; ++nt) {
            const int cc = wn + nt * 16 + (lane & 15);
#pragma unroll
            for (int r = 0; r < 4; ++r)
                lds[(r0 + r) * BN2 + cc] = (ushort_t)f2bf(acc[mt][nt][r]);
        }
    }
    __syncthreads();

    // temporal phase: thread = (w-group wg, e-quad eq4); 12-row register window from LDS.
    const int eq4  = (tid & 31) * 4;
    const int wg   = tid >> 5;
    const int wlim = lt ? (NW - 128) : 128;         // 116 or 128 valid w's in this tile
    const int wbeg = wg * 16;
    const int wend = (wbeg + 16 < wlim) ? (wbeg + 16) : wlim;
    const float4 Sv  = *(const float4*)(S + n0 + eq4);
    const float4 bsv = *(const float4*)(bs + n0 + eq4);

    for (int wl = wbeg; wl < wend; ++wl) {
        float win[PAST][4];
#pragma unroll
        for (int p = 0; p < PAST; ++p) {
            const uint2 v = *(const uint2*)(lds + (wl + p) * BN2 + eq4);
            win[p][0] = __uint_as_float(v.x << 16);
            win[p][1] = __uint_as_float(v.x & 0xffff0000u);
            win[p][2] = __uint_as_float(v.y << 16);
            win[p][3] = __uint_as_float(v.y & 0xffff0000u);
        }
        float* orow = Out + ((size_t)(b * NW + lt * 128 + wl) * FUTURE) * ND + n0 + eq4;
#pragma unroll
        for (int f = 0; f < FUTURE; ++f) {
            const float btf = bt[f];                 // uniform -> SGPR
            float a0 = fmaf(btf, Sv.x, bsv.x);
            float a1 = fmaf(btf, Sv.y, bsv.y);
            float a2 = fmaf(btf, Sv.z, bsv.z);
            float a3 = fmaf(btf, Sv.w, bsv.w);
#pragma unroll
            for (int p = 0; p < PAST; ++p) {
                const float c = Wt[f * PAST + p];    // uniform -> SGPR
                a0 = fmaf(c, win[p][0], a0);
                a1 = fmaf(c, win[p][1], a1);
                a2 = fmaf(c, win[p][2], a2);
                a3 = fmaf(c, win[p][3], a3);
            }
            *(float4*)(orow + (size_t)f * ND) = make_float4(a0, a1, a2, a3);
        }
    }
}

// ---------------- launch ----------------
extern "C" void kernel_launch(void* const* d_in, const int* in_sizes, int n_in,
                              void* d_out, int out_size, void* d_ws, size_t ws_size,
                              hipStream_t stream) {
    const float* inp = (const float*)d_in[0];  // [64,256,512] fp32
    const float* Wt  = (const float*)d_in[1];  // [12,12]
    const float* bt  = (const float*)d_in[2];  // [12]
    const float* Ws  = (const float*)d_in[3];  // [512,512]
    const float* bs  = (const float*)d_in[4];  // [512]
    float* out = (float*)d_out;

    ushort_t* Ws_b = (ushort_t*)d_ws;                                    // 512 KB
    float*    S    = (float*)((char*)d_ws + (size_t)ND * ND * sizeof(ushort_t));

    prep_ws<<<dim3(ND), dim3(256), 0, stream>>>(Ws, Ws_b, S);
    fused<<<dim3(ND / BN2, NB * 2), dim3(256), 0, stream>>>(inp, Ws_b, Wt, bt, bs, S, out);
}

// Round 2
// 437.625 us; speedup vs baseline: 1.1450x; 1.1450x over previous
//
#include <hip/hip_runtime.h>

#define PAST 12
#define FUTURE 12
#define NB 64
#define NL 256
#define ND 512
#define NW 244  // NL - PAST

typedef unsigned short ushort_t;
typedef __attribute__((ext_vector_type(8))) short short8;
typedef __attribute__((ext_vector_type(4))) float floatx4;

__device__ inline unsigned int f2bf(float x) {
    unsigned int u = __float_as_uint(x);
    return (u + 0x7fffu + ((u >> 16) & 1u)) >> 16;  // RNE
}

// ---------------- Stage 0: W_s fp32 -> bf16, and S[e] = sum_d W_s[e][d] ----------------
__global__ __launch_bounds__(256) void prep_ws(
    const float* __restrict__ Ws, ushort_t* __restrict__ Wsb, float* __restrict__ S)
{
    const int row = blockIdx.x;       // 0..511
    const int t = threadIdx.x;        // 0..255
    const float2 v = *(const float2*)(Ws + (size_t)row * ND + t * 2);
    *(unsigned int*)(Wsb + (size_t)row * ND + t * 2) = f2bf(v.x) | (f2bf(v.y) << 16);
    float s = v.x + v.y;
#pragma unroll
    for (int o = 32; o > 0; o >>= 1) s += __shfl_down(s, o);
    __shared__ float red[4];
    if ((t & 63) == 0) red[t >> 6] = s;
    __syncthreads();
    if (t == 0) S[row] = red[0] + red[1] + red[2] + red[3];
}

// ---------------- Stage 1: y = inp @ W_s^T  (NT bf16 MFMA GEMM, fp32 A converted in-flight) ----------------
#define BM 128
#define BN 128
#define BK 32

// A staging: thread handles i = c*256+tid, c<4; row = i>>3, float4-chunk = i&7.
#define STAGE_A_LOAD(k0) do { \
    _Pragma("unroll") \
    for (int c = 0; c < 4; ++c) av[c] = *(const float4*)(aptr[c] + (k0)); \
} while (0)

#define STAGE_A_WRITE(dst) do { \
    _Pragma("unroll") \
    for (int c = 0; c < 4; ++c) { \
        uint2 o; \
        o.x = f2bf(av[c].x) | (f2bf(av[c].y) << 16); \
        o.y = f2bf(av[c].z) | (f2bf(av[c].w) << 16); \
        *(uint2*)((dst) + tid * 4 + c * 1024) = o; \
    } \
} while (0)

#define STAGE_B(k0, dst) do { \
    _Pragma("unroll") \
    for (int r = 0; r < 2; ++r) { \
        const ushort_t* gb = Bm + (size_t)(n0 + (tid >> 2) + r * 64) * ND + (k0) + (tid & 3) * 8; \
        __builtin_amdgcn_global_load_lds( \
            (const __attribute__((address_space(1))) unsigned int*)gb, \
            (__attribute__((address_space(3))) unsigned int*)((dst) + r * 2048 + tid * 8), \
            16, 0, 0); \
    } \
} while (0)

#define GEMM_STEP(cura, curb) do { \
    const ushort_t* a_base = (cura) + (wm + (lane & 15)) * BK + (lane >> 4) * 8; \
    const ushort_t* b_base = (curb) + (wn + (lane & 15)) * BK + (lane >> 4) * 8; \
    short8 af[4], bq[4]; \
    _Pragma("unroll") \
    for (int t = 0; t < 4; ++t) { \
        af[t] = *(const short8*)(a_base + t * 16 * BK); \
        bq[t] = *(const short8*)(b_base + t * 16 * BK); \
    } \
    _Pragma("unroll") \
    for (int i = 0; i < 4; ++i) \
    _Pragma("unroll") \
    for (int j = 0; j < 4; ++j) \
        acc[i][j] = __builtin_amdgcn_mfma_f32_16x16x32_bf16(af[i], bq[j], acc[i][j], 0, 0, 0); \
} while (0)

#define FULL_STEP(k, cura, curb, nxta, nxtb) do { \
    if ((k) < 15) { STAGE_A_LOAD(((k) + 1) * BK); STAGE_B(((k) + 1) * BK, nxtb); } \
    GEMM_STEP(cura, curb); \
    if ((k) < 15) STAGE_A_WRITE(nxta); \
    __syncthreads(); \
} while (0)

__global__ __launch_bounds__(256) void gemm_spatial(
    const float* __restrict__ A,       // inp [16384, 512] fp32
    const ushort_t* __restrict__ Bm,   // Ws bf16 [512, 512]
    ushort_t* __restrict__ Y)          // [16384, 512] bf16
{
    __shared__ __align__(16) ushort_t As0[BM * BK];
    __shared__ __align__(16) ushort_t As1[BM * BK];
    __shared__ __align__(16) ushort_t Bs0[BN * BK];
    __shared__ __align__(16) ushort_t Bs1[BN * BK];

    const int tid  = threadIdx.x;
    const int wave = tid >> 6;
    const int lane = tid & 63;
    const int m0 = blockIdx.y * BM;
    const int n0 = blockIdx.x * BN;
    const int wm = (wave >> 1) * 64;
    const int wn = (wave & 1) * 64;

    floatx4 acc[4][4] = {};

    const float* aptr[4];
#pragma unroll
    for (int c = 0; c < 4; ++c) {
        const int i = c * 256 + tid;
        aptr[c] = A + (size_t)(m0 + (i >> 3)) * ND + (i & 7) * 4;
    }

    float4 av[4];

    // prologue: tile 0 into buf0
    STAGE_A_LOAD(0);
    STAGE_B(0, Bs0);
    STAGE_A_WRITE(As0);
    __syncthreads();

    for (int k = 0; k < 16; k += 2) {
        FULL_STEP(k,     As0, Bs0, As1, Bs1);
        FULL_STEP(k + 1, As1, Bs1, As0, Bs0);
    }

#pragma unroll
    for (int i = 0; i < 4; ++i) {
        const int m_base = m0 + wm + i * 16 + (lane >> 4) * 4;
#pragma unroll
        for (int j = 0; j < 4; ++j) {
            const int n = n0 + wn + j * 16 + (lane & 15);
#pragma unroll
            for (int r = 0; r < 4; ++r) {
                Y[(size_t)(m_base + r) * ND + n] = (ushort_t)f2bf(acc[i][j][r]);
            }
        }
    }
}

// ---------------- Stage 2: temporal mix + biases (fp32 out, float4 stores) ----------------
// out[b,w,f,e] = sum_p W_t[f,p]*y[b,w+p,e] + b_t[f]*S[e] + b_s[e]
// Block: 256 threads = 2 halves of 128. Half h covers w in [w0+4h, w0+4h+3],
// thread owns e-quad eq = (tid&127)*4. Window: 15 rows x 4 floats in VGPRs.
#define WTILE 8

__global__ __launch_bounds__(256) void temporal_kernel(
    const ushort_t* __restrict__ Y,    // [64*256, 512] bf16
    const float*    __restrict__ Wt,   // [12,12] fp32 (wave-uniform -> s_load)
    const float*    __restrict__ bt,   // [12] fp32
    const float*    __restrict__ bs,   // [512] fp32
    const float*    __restrict__ S,    // [512] fp32
    float*          __restrict__ Out)  // [64,244,12,512] fp32
{
    const int tid = threadIdx.x;
    const int b  = blockIdx.y;
    const int w0 = blockIdx.x * WTILE + (tid >> 7) * 4;  // half-block w-base
    const int eq = (tid & 127) * 4;

    const float4 Sv  = *(const float4*)(S + eq);
    const float4 bsv = *(const float4*)(bs + eq);

    // 15-row sliding window, 4 e's per thread, registers only (all indices constant)
    float win[PAST + 3][4];
    const ushort_t* ybase = Y + ((size_t)(b * NL + w0)) * ND + eq;
#pragma unroll
    for (int i = 0; i < PAST + 3; ++i) {
        if (w0 + i < NL) {
            const uint2 v = *(const uint2*)(ybase + (size_t)i * ND);
            win[i][0] = __uint_as_float(v.x << 16);
            win[i][1] = __uint_as_float(v.x & 0xffff0000u);
            win[i][2] = __uint_as_float(v.y << 16);
            win[i][3] = __uint_as_float(v.y & 0xffff0000u);
        } else {
            win[i][0] = win[i][1] = win[i][2] = win[i][3] = 0.f;
        }
    }

#pragma unroll
    for (int w = 0; w < 4; ++w) {
        if (w0 + w < NW) {
            float* orow = Out + ((size_t)(b * NW + (w0 + w)) * FUTURE) * ND + eq;
#pragma unroll
            for (int f = 0; f < FUTURE; ++f) {
                const float btf = bt[f];                    // uniform -> SGPR
                float a0 = fmaf(btf, Sv.x, bsv.x);
                float a1 = fmaf(btf, Sv.y, bsv.y);
                float a2 = fmaf(btf, Sv.z, bsv.z);
                float a3 = fmaf(btf, Sv.w, bsv.w);
#pragma unroll
                for (int p = 0; p < PAST; ++p) {
                    const float c = Wt[f * PAST + p];       // uniform -> SGPR
                    a0 = fmaf(c, win[w + p][0], a0);
                    a1 = fmaf(c, win[w + p][1], a1);
                    a2 = fmaf(c, win[w + p][2], a2);
                    a3 = fmaf(c, win[w + p][3], a3);
                }
                *(float4*)(orow + (size_t)f * ND) = make_float4(a0, a1, a2, a3);
            }
        }
    }
}

// ---------------- launch ----------------
extern "C" void kernel_launch(void* const* d_in, const int* in_sizes, int n_in,
                              void* d_out, int out_size, void* d_ws, size_t ws_size,
                              hipStream_t stream) {
    const float* inp = (const float*)d_in[0];  // [64,256,512] fp32
    const float* Wt  = (const float*)d_in[1];  // [12,12]
    const float* bt  = (const float*)d_in[2];  // [12]
    const float* Ws  = (const float*)d_in[3];  // [512,512]
    const float* bs  = (const float*)d_in[4];  // [512]
    float* out = (float*)d_out;

    const size_t n_inp = (size_t)NB * NL * ND;            // 16,777,216
    ushort_t* Y    = (ushort_t*)d_ws;                               // 33.5 MB
    ushort_t* Ws_b = (ushort_t*)((char*)d_ws + n_inp * 2);          // +0.5 MB
    float*    S    = (float*)((char*)d_ws + n_inp * 2 + (size_t)ND * ND * 2);

    prep_ws<<<dim3(ND), dim3(256), 0, stream>>>(Ws, Ws_b, S);
    gemm_spatial<<<dim3(ND / BN, (NB * NL) / BM), dim3(256), 0, stream>>>(inp, Ws_b, Y);
    temporal_kernel<<<dim3((NW + WTILE - 1) / WTILE, NB), dim3(256), 0, stream>>>(Y, Wt, bt, bs, S, out);
}

// Round 4
// 431.256 us; speedup vs baseline: 1.1619x; 1.0148x over previous
//
#include <hip/hip_runtime.h>

#define PAST 12
#define FUTURE 12
#define NB 64
#define NL 256
#define ND 512
#define NW 244  // NL - PAST

typedef unsigned short ushort_t;
typedef __attribute__((ext_vector_type(8))) short short8;
typedef __attribute__((ext_vector_type(4))) float floatx4;

__device__ inline unsigned int f2bf(float x) {
    unsigned int u = __float_as_uint(x);
    return (u + 0x7fffu + ((u >> 16) & 1u)) >> 16;  // RNE
}

// ---------------- Stage 0: W_s fp32 -> bf16, and S[e] = sum_d W_s[e][d] ----------------
__global__ __launch_bounds__(256) void prep_ws(
    const float* __restrict__ Ws, ushort_t* __restrict__ Wsb, float* __restrict__ S)
{
    const int row = blockIdx.x;       // 0..511
    const int t = threadIdx.x;        // 0..255
    const float2 v = *(const float2*)(Ws + (size_t)row * ND + t * 2);
    *(unsigned int*)(Wsb + (size_t)row * ND + t * 2) = f2bf(v.x) | (f2bf(v.y) << 16);
    float s = v.x + v.y;
#pragma unroll
    for (int o = 32; o > 0; o >>= 1) s += __shfl_down(s, o);
    __shared__ float red[4];
    if ((t & 63) == 0) red[t >> 6] = s;
    __syncthreads();
    if (t == 0) S[row] = red[0] + red[1] + red[2] + red[3];
}

// ---------------- Stage 1: y = inp @ W_s^T  (NT bf16 MFMA GEMM, fp32 A converted in-flight) ----------------
// BM=64 -> 1024 blocks (4/CU). Chunked XCD swizzle: XCD k owns m-panels [128k/8...],
// n-blocks of one m-panel adjacent -> A read once from HBM, re-read from own L2.
#define BM 64
#define BN 128
#define BK 32

// A staging: thread handles 8 consecutive k's: row = tid>>2, kc = (tid&3)*8.
#define STAGE_A_LOAD(k0) do { \
    av0 = *(const float4*)(aptr + (k0)); \
    av1 = *(const float4*)(aptr + (k0) + 4); \
} while (0)

#define STAGE_A_WRITE(dst) do { \
    uint4 o; \
    o.x = f2bf(av0.x) | (f2bf(av0.y) << 16); \
    o.y = f2bf(av0.z) | (f2bf(av0.w) << 16); \
    o.z = f2bf(av1.x) | (f2bf(av1.y) << 16); \
    o.w = f2bf(av1.z) | (f2bf(av1.w) << 16); \
    *(uint4*)((dst) + tid * 8) = o; \
} while (0)

#define STAGE_B(k0, dst) do { \
    _Pragma("unroll") \
    for (int r = 0; r < 2; ++r) { \
        const ushort_t* gb = Bm + (size_t)(n0 + (tid >> 2) + r * 64) * ND + (k0) + (tid & 3) * 8; \
        __builtin_amdgcn_global_load_lds( \
            (const __attribute__((address_space(1))) unsigned int*)gb, \
            (__attribute__((address_space(3))) unsigned int*)((dst) + r * 2048 + tid * 8), \
            16, 0, 0); \
    } \
} while (0)

#define GEMM_STEP(cura, curb) do { \
    const ushort_t* a_base = (cura) + (wm + (lane & 15)) * BK + (lane >> 4) * 8; \
    const ushort_t* b_base = (curb) + (wn + (lane & 15)) * BK + (lane >> 4) * 8; \
    short8 af[2], bq[4]; \
    _Pragma("unroll") \
    for (int t = 0; t < 2; ++t) af[t] = *(const short8*)(a_base + t * 16 * BK); \
    _Pragma("unroll") \
    for (int t = 0; t < 4; ++t) bq[t] = *(const short8*)(b_base + t * 16 * BK); \
    _Pragma("unroll") \
    for (int i = 0; i < 2; ++i) \
    _Pragma("unroll") \
    for (int j = 0; j < 4; ++j) \
        acc[i][j] = __builtin_amdgcn_mfma_f32_16x16x32_bf16(af[i], bq[j], acc[i][j], 0, 0, 0); \
} while (0)

#define FULL_STEP(k, cura, curb, nxta, nxtb) do { \
    if ((k) < 15) { STAGE_A_LOAD(((k) + 1) * BK); STAGE_B(((k) + 1) * BK, nxtb); } \
    GEMM_STEP(cura, curb); \
    if ((k) < 15) STAGE_A_WRITE(nxta); \
    __syncthreads(); \
} while (0)

__global__ __launch_bounds__(256) void gemm_spatial(
    const float* __restrict__ A,       // inp [16384, 512] fp32
    const ushort_t* __restrict__ Bm,   // Ws bf16 [512, 512]
    ushort_t* __restrict__ Y)          // [16384, 512] bf16
{
    __shared__ __align__(16) ushort_t As0[BM * BK];
    __shared__ __align__(16) ushort_t As1[BM * BK];
    __shared__ __align__(16) ushort_t Bs0[BN * BK];
    __shared__ __align__(16) ushort_t Bs1[BN * BK];

    const int tid  = threadIdx.x;
    const int wave = tid >> 6;
    const int lane = tid & 63;

    // bijective chunked XCD swizzle (1024 blocks, 1024 % 8 == 0): XCD k gets idx [128k, 128k+128)
    const int bid = blockIdx.x;
    const int idx = (bid & 7) * 128 + (bid >> 3);
    const int n0 = (idx & 3) * BN;     // n fastest: 4 n-blocks of one m-panel adjacent in-XCD
    const int m0 = (idx >> 2) * BM;
    const int wm = (wave >> 1) * 32;
    const int wn = (wave & 1) * 64;

    floatx4 acc[2][4] = {};

    const float* aptr = A + (size_t)(m0 + (tid >> 2)) * ND + (tid & 3) * 8;
    float4 av0, av1;

    // prologue: tile 0 into buf0
    STAGE_A_LOAD(0);
    STAGE_B(0, Bs0);
    STAGE_A_WRITE(As0);
    __syncthreads();

    for (int k = 0; k < 16; k += 2) {
        FULL_STEP(k,     As0, Bs0, As1, Bs1);
        FULL_STEP(k + 1, As1, Bs1, As0, Bs0);
    }

#pragma unroll
    for (int i = 0; i < 2; ++i) {
        const int m_base = m0 + wm + i * 16 + (lane >> 4) * 4;
#pragma unroll
        for (int j = 0; j < 4; ++j) {
            const int n = n0 + wn + j * 16 + (lane & 15);
#pragma unroll
            for (int r = 0; r < 4; ++r) {
                Y[(size_t)(m_base + r) * ND + n] = (ushort_t)f2bf(acc[i][j][r]);
            }
        }
    }
}

// ---------------- Stage 2: temporal mix + biases (fp32 out, nontemporal float4 stores) ----------------
// out[b,w,f,e] = sum_p W_t[f,p]*y[b,w+p,e] + b_t[f]*S[e] + b_s[e]
// Chunked XCD swizzle: XCD k <- batches [8k, 8k+8), matching the GEMM's Y placement
// (GEMM XCD k wrote m-panels [32k,32k+32) = rows [2048k, 2048(k+1)) = batches [8k,8k+8)).
#define WTILE 8
#define TGRID (((NW + WTILE - 1) / WTILE) * NB)   // 31 * 64 = 1984, % 8 == 0

__global__ __launch_bounds__(256) void temporal_kernel(
    const ushort_t* __restrict__ Y,    // [64*256, 512] bf16
    const float*    __restrict__ Wt,   // [12,12] fp32 (wave-uniform -> s_load)
    const float*    __restrict__ bt,   // [12] fp32
    const float*    __restrict__ bs,   // [512] fp32
    const float*    __restrict__ S,    // [512] fp32
    float*          __restrict__ Out)  // [64,244,12,512] fp32
{
    const int tid = threadIdx.x;
    const int bid = blockIdx.x;
    const int idx = (bid & 7) * (TGRID / 8) + (bid >> 3);   // bijective (1984 % 8 == 0)
    const int b   = idx / 31;          // XCD k gets b in [8k, 8k+8)
    const int wx  = idx % 31;
    const int w0 = wx * WTILE + (tid >> 7) * 4;  // half-block w-base
    const int eq = (tid & 127) * 4;

    const float4 Sv  = *(const float4*)(S + eq);
    const float4 bsv = *(const float4*)(bs + eq);

    // 15-row sliding window, 4 e's per thread, registers only (all indices constant)
    float win[PAST + 3][4];
    const ushort_t* ybase = Y + ((size_t)(b * NL + w0)) * ND + eq;
#pragma unroll
    for (int i = 0; i < PAST + 3; ++i) {
        if (w0 + i < NL) {
            const uint2 v = *(const uint2*)(ybase + (size_t)i * ND);
            win[i][0] = __uint_as_float(v.x << 16);
            win[i][1] = __uint_as_float(v.x & 0xffff0000u);
            win[i][2] = __uint_as_float(v.y << 16);
            win[i][3] = __uint_as_float(v.y & 0xffff0000u);
        } else {
            win[i][0] = win[i][1] = win[i][2] = win[i][3] = 0.f;
        }
    }

#pragma unroll
    for (int w = 0; w < 4; ++w) {
        if (w0 + w < NW) {
            float* orow = Out + ((size_t)(b * NW + (w0 + w)) * FUTURE) * ND + eq;
#pragma unroll
            for (int f = 0; f < FUTURE; ++f) {
                const float btf = bt[f];                    // uniform -> SGPR
                float a0 = fmaf(btf, Sv.x, bsv.x);
                float a1 = fmaf(btf, Sv.y, bsv.y);
                float a2 = fmaf(btf, Sv.z, bsv.z);
                float a3 = fmaf(btf, Sv.w, bsv.w);
#pragma unroll
                for (int p = 0; p < PAST; ++p) {
                    const float c = Wt[f * PAST + p];       // uniform -> SGPR
                    a0 = fmaf(c, win[w + p][0], a0);
                    a1 = fmaf(c, win[w + p][1], a1);
                    a2 = fmaf(c, win[w + p][2], a2);
                    a3 = fmaf(c, win[w + p][3], a3);
                }
                // streaming output, never re-read: bypass L2/L3, keep them for Y.
                // NOTE: must use ext_vector float4 (floatx4), not HIP_vector_type float4.
                floatx4 ov;
                ov.x = a0; ov.y = a1; ov.z = a2; ov.w = a3;
                __builtin_nontemporal_store(ov, (floatx4*)(orow + (size_t)f * ND));
            }
        }
    }
}

// ---------------- launch ----------------
extern "C" void kernel_launch(void* const* d_in, const int* in_sizes, int n_in,
                              void* d_out, int out_size, void* d_ws, size_t ws_size,
                              hipStream_t stream) {
    const float* inp = (const float*)d_in[0];  // [64,256,512] fp32
    const float* Wt  = (const float*)d_in[1];  // [12,12]
    const float* bt  = (const float*)d_in[2];  // [12]
    const float* Ws  = (const float*)d_in[3];  // [512,512]
    const float* bs  = (const float*)d_in[4];  // [512]
    float* out = (float*)d_out;

    const size_t n_inp = (size_t)NB * NL * ND;            // 16,777,216
    ushort_t* Y    = (ushort_t*)d_ws;                               // 33.5 MB
    ushort_t* Ws_b = (ushort_t*)((char*)d_ws + n_inp * 2);          // +0.5 MB
    float*    S    = (float*)((char*)d_ws + n_inp * 2 + (size_t)ND * ND * 2);

    prep_ws<<<dim3(ND), dim3(256), 0, stream>>>(Ws, Ws_b, S);
    gemm_spatial<<<dim3((NB * NL / BM) * (ND / BN)), dim3(256), 0, stream>>>(inp, Ws_b, Y);
    temporal_kernel<<<dim3(TGRID), dim3(256), 0, stream>>>(Y, Wt, bt, bs, S, out);
}